// Round 7
// baseline (741.556 us; speedup 1.0000x reference)
//
#include <hip/hip_runtime.h>
#include <hip/hip_bf16.h>
#include <math.h>

#define BB 8
#define NN 64
#define TT 1024
#define KK 12
#define BKT (BB*KK*TT)   // 98304
#define W2SS 2312        // shorts per kc chunk in LDS w2s

typedef short bf16x8 __attribute__((ext_vector_type(8)));
typedef float f32x4  __attribute__((ext_vector_type(4)));

__device__ __forceinline__ float fast_rcp(float x)  { return __builtin_amdgcn_rcpf(x); }
__device__ __forceinline__ float fast_exp2(float x) { return __builtin_amdgcn_exp2f(x); }
__device__ __forceinline__ float fast_log2(float x) { return __builtin_amdgcn_logf(x); }

__device__ __forceinline__ float fast_softplus(float x) {
    float a = fabsf(x);
    float e = fast_exp2(-1.44269504f * a);
    float l = fast_log2(1.0f + e) * 0.69314718f;
    return fmaxf(x, 0.0f) + l;
}
__device__ __forceinline__ float fast_tanh(float x) {
    float t = fast_exp2(x * 2.885390082f);       // e^(2x)
    return fmaf(-2.0f, fast_rcp(t + 1.0f), 1.0f);
}
// Abramowitz-Stegun 7.1.26, |err| <= 1.5e-7
__device__ __forceinline__ float fast_erf(float x) {
    float ax = fabsf(x);
    float t  = fast_rcp(fmaf(0.3275911f, ax, 1.0f));
    float p  = fmaf(fmaf(fmaf(fmaf(1.061405429f, t, -1.453152027f), t,
                   1.421413741f), t, -0.284496736f), t, 0.254829592f) * t;
    float e  = fast_exp2(-1.44269504f * ax * ax);
    float r  = fmaf(-p, e, 1.0f);
    return copysignf(r, x);
}
__device__ __forceinline__ float fast_gelu(float x) {
    return 0.5f * x * (1.0f + fast_erf(x * 0.70710678118654752f));
}
__device__ __forceinline__ short f2bf(float x) {
    return (short)__builtin_bit_cast(unsigned short, __float2bfloat16(x));
}

// ---------------------------------------------------------------------------
// Kernel 1: per-(b,k,t) lead geometry -> ws: lead[18][BKT]
// ---------------------------------------------------------------------------
__global__ void prep_lead(const float* __restrict__ chest_offset,
                          const float* __restrict__ resp_freq,
                          const float* __restrict__ resp_vec,
                          const float* __restrict__ limb_ra,
                          const float* __restrict__ limb_la,
                          const float* __restrict__ limb_ll,
                          const float* __restrict__ chest_vectors,
                          float* __restrict__ lead)
{
    int id = blockIdx.x * blockDim.x + threadIdx.x;
    if (id >= BKT) return;
    int t  = id & (TT - 1);
    int bk = id >> 10;
    int k  = bk % KK;
    int b  = bk / KK;

    float lx, ly, lz;
    if (k < 6) {
        float rax = limb_ra[0], ray = limb_ra[1], raz = limb_ra[2];
        float lax = limb_la[0], lay = limb_la[1], laz = limb_la[2];
        float llx = limb_ll[0], lly = limb_ll[1], llz = limb_ll[2];
        float dx, dy, dz;
        switch (k) {
            case 0: dx = lax - rax; dy = lay - ray; dz = laz - raz; break;
            case 1: dx = llx - rax; dy = lly - ray; dz = llz - raz; break;
            case 2: dx = llx - lax; dy = lly - lay; dz = llz - laz; break;
            case 3: dx = rax - 0.5f*(lax+llx); dy = ray - 0.5f*(lay+lly); dz = raz - 0.5f*(laz+llz); break;
            case 4: dx = lax - 0.5f*(rax+llx); dy = lay - 0.5f*(ray+lly); dz = laz - 0.5f*(raz+llz); break;
            default:dx = llx - 0.5f*(rax+lax); dy = lly - 0.5f*(ray+lay); dz = llz - 0.5f*(raz+laz); break;
        }
        float n   = sqrtf(dx*dx + dy*dy + dz*dz);
        float inv = 1.0f / fmaxf(n, 1e-6f);
        lx = dx*inv; ly = dy*inv; lz = dz*inv;
    } else {
        int j = k - 6;
        float cx = chest_vectors[j*3+0], cy = chest_vectors[j*3+1], cz = chest_vectors[j*3+2];
        float n   = sqrtf(cx*cx + cy*cy + cz*cz);
        float inv = 1.0f / fmaxf(n, 1e-12f);
        cx *= inv; cy *= inv; cz *= inv;
        cx += chest_offset[(b*6+j)*3+0];
        cy += chest_offset[(b*6+j)*3+1];
        cz += chest_offset[(b*6+j)*3+2];
        n   = sqrtf(cx*cx + cy*cy + cz*cz);
        inv = 1.0f / fmaxf(n, 1e-12f);
        lx = cx*inv; ly = cy*inv; lz = cz*inv;
    }

    float tl = t * (1.0f / (TT - 1));
    float ph = 6.283185307179586f * resp_freq[b] * tl;
    float sv = sinf(ph);
    float Lx = lx + resp_vec[b*3+0] * sv;
    float Ly = ly + resp_vec[b*3+1] * sv;
    float Lz = lz + resp_vec[b*3+2] * sv;
    float n   = sqrtf(Lx*Lx + Ly*Ly + Lz*Lz);
    float inv = 1.0f / fmaxf(n, 1e-12f);
    Lx *= inv; Ly *= inv; Lz *= inv;

    float e1x = 0.0f, e1y = Lz, e1z = -Ly;
    float n1  = sqrtf(e1y*e1y + e1z*e1z);
    if (n1 < 1e-4f) { e1x = -Lz; e1y = 0.0f; e1z = Lx; }
    float ne1 = sqrtf(e1x*e1x + e1y*e1y + e1z*e1z);
    inv = 1.0f / fmaxf(ne1, 1e-6f);
    e1x *= inv; e1y *= inv; e1z *= inv;

    float e2x = e1y*Lz - e1z*Ly;
    float e2y = e1z*Lx - e1x*Lz;
    float e2z = e1x*Ly - e1y*Lx;
    float ne2 = sqrtf(e2x*e2x + e2y*e2y + e2z*e2z);
    inv = 1.0f / fmaxf(ne2, 1e-6f);
    e2x *= inv; e2y *= inv; e2z *= inv;

    lead[ 0*BKT + id] = Lx;
    lead[ 1*BKT + id] = Ly;
    lead[ 2*BKT + id] = Lz;
    lead[ 3*BKT + id] = e1x;
    lead[ 4*BKT + id] = e1y;
    lead[ 5*BKT + id] = e1z;
    lead[ 6*BKT + id] = e2x;
    lead[ 7*BKT + id] = e2y;
    lead[ 8*BKT + id] = e2z;
    lead[ 9*BKT + id] = 0.282095f;
    lead[10*BKT + id] = -0.488603f * Ly;
    lead[11*BKT + id] =  0.488603f * Lz;
    lead[12*BKT + id] = -0.488603f * Lx;
    lead[13*BKT + id] =  1.092548f * Lx * Ly;
    lead[14*BKT + id] = -1.092548f * Ly * Lz;
    lead[15*BKT + id] =  0.315392f * (3.0f * Lz * Lz - 1.0f);
    lead[16*BKT + id] = -1.092548f * Lx * Lz;
    lead[17*BKT + id] =  0.546274f * (Lx * Lx - Ly * Ly);
}

// ---------------------------------------------------------------------------
// Kernel 2: w2 [k][oc][ic][tap] f32 -> w2bf [k][kc][tap][oc][8ic] bf16
// ---------------------------------------------------------------------------
__global__ void prep_w2bf(const float* __restrict__ w2, unsigned short* __restrict__ out)
{
    int id = blockIdx.x * blockDim.x + threadIdx.x;
    if (id >= KK*4*9*32*8) return;
    int j   = id & 7;
    int r1  = id >> 3;
    int oc  = r1 & 31;
    int r2  = r1 >> 5;
    int tap = r2 % 9;
    int r3  = r2 / 9;
    int kc  = r3 & 3;
    int k   = r3 >> 2;
    float v = w2[((k*32 + oc)*32 + (kc*8 + j))*9 + tap];
    out[id] = __builtin_bit_cast(unsigned short, __float2bfloat16(v));
}

// ---------------------------------------------------------------------------
// Kernel 3: fused splat + CNN (conv2 via bf16 MFMA 16x16x32).
// [round-2 structure + fast transcendentals + barrier-protected LDS handoff]
// The qbuf float4->float re-type (inbw alias) is a WAR hazard the COMPILER
// may reorder when transcendentals are inlined (R6 failure); __syncthreads()
// between the splat reads and the aliased overwrite pins the order.
// ---------------------------------------------------------------------------
__global__ __launch_bounds__(256, 3) void fused_main(
    const float* __restrict__ mu,       const float* __restrict__ sigma0,
    const float* __restrict__ sigma_vel,const float* __restrict__ amplitude,
    const float* __restrict__ sh_base,  const float* __restrict__ sh_vel,
    const float* __restrict__ p0,       const float* __restrict__ p_vel,
    const float* __restrict__ tau_raw,
    const float* __restrict__ w1,       const float* __restrict__ b1,
    const unsigned short* __restrict__ w2bf, const float* __restrict__ b2,
    const float* __restrict__ wf,       const float* __restrict__ bfp,
    const float* __restrict__ lead,     float* __restrict__ out)
{
    // LDS: 18496 + 25600 + 8192 = 52288 B -> 3 blocks/CU
    __shared__ __align__(16) short  w2s[4*W2SS];     // [kc][tap][oc][8ic] bf16, padded stride
    __shared__ __align__(16) short  h1c[4][3200];    // per wave: [kc=4][100 padpix][8 ic] bf16
    __shared__ __align__(16) float4 qbuf[4][2][64];  // per wave: phase1 out; later aliased as padded inb

    const int wave = threadIdx.x >> 6;
    const int lane = threadIdx.x & 63;
    const int bid  = blockIdx.x;
    const int ig   = bid & 127;
    const int k    = (bid >> 7) % KK;
    const int b    = bid / (128 * KK);
    const int i    = ig * 4 + wave;
    const int t0   = 2 * i;

    // ---- stage w2 bf16 fragments into LDS (block-shared) ----
    {
        const unsigned* w2u = (const unsigned*)(w2bf + k * 9216);
        for (int idx = threadIdx.x; idx < 4608; idx += 256) {
            unsigned v = w2u[idx];
            int sp  = idx << 1;
            int kc  = sp / 2304;
            int rem = sp - kc * 2304;
            *(unsigned*)&w2s[kc * W2SS + rem] = v;
        }
    }
    // ---- zero this wave's h1c (border stays 0 forever) ----
    {
        unsigned* hz = (unsigned*)&h1c[wave][0];
        #pragma unroll
        for (int j = 0; j < 25; ++j) hz[lane + j*64] = 0u;
    }
    __syncthreads();   // w2s + h1c-zero readiness

    // ---------------- phase 1: per-n quantities (lane = n) ----------------
    {
        const int n  = lane;
        const int bn = b * NN + n;
        const float muv = mu[bn], s0v = sigma0[bn], svv = sigma_vel[bn], amp = amplitude[bn];
        const float p0x = p0[bn*3+0], p0y = p0[bn*3+1], p0z = p0[bn*3+2];
        const float pvx = p_vel[bn*3+0], pvy = p_vel[bn*3+1], pvz = p_vel[bn*3+2];
        float shb[9], shv[9];
        #pragma unroll
        for (int m = 0; m < 9; ++m) { shb[m] = sh_base[bn*9+m]; shv[m] = sh_vel[bn*9+m]; }

        #pragma unroll
        for (int tt = 0; tt < 2; ++tt) {
            const int t  = t0 + tt;
            const int li = (b*KK + k)*TT + t;      // wave-uniform -> s_load
            const float Lx  = lead[0*BKT+li], Ly  = lead[1*BKT+li], Lz  = lead[2*BKT+li];
            const float e1x = lead[3*BKT+li], e1y = lead[4*BKT+li], e1z = lead[5*BKT+li];
            const float e2x = lead[6*BKT+li], e2y = lead[7*BKT+li], e2z = lead[8*BKT+li];
            float Yv[9];
            #pragma unroll
            for (int m = 0; m < 9; ++m) Yv[m] = lead[(9+m)*BKT + li];

            const float tl = t * (1.0f / (TT - 1));
            const float dt = tl - muv;
            const float sig = fast_softplus(s0v + svv*dt) + 0.001f;
            const float z   = dt * fast_rcp(sig);
            const float g   = amp * fast_exp2(-0.721347520f * z * z);
            float px = p0x + pvx*dt, py = p0y + pvy*dt, pz = p0z + pvz*dt;
            const float pn   = sqrtf(px*px + py*py + pz*pz);
            const float pinv = fast_rcp(fmaxf(pn, 1e-6f));
            px *= pinv; py *= pinv; pz *= pinv;
            const float u    = fast_tanh(px*e1x + py*e1y + pz*e1z);
            const float v    = fast_tanh(px*e2x + py*e2y + pz*e2z);
            const float hem  = fmaxf(px*Lx + py*Ly + pz*Lz, 0.0f);
            const float a    = g * hem;
            float shp = 0.0f;
            #pragma unroll
            for (int m = 0; m < 9; ++m) shp = fmaf(fmaf(shv[m], dt, shb[m]), Yv[m], shp);
            qbuf[wave][tt][n] = make_float4(u, v, a, a * shp);
        }
    }
    __syncthreads();   // qbuf writes visible / ordered before splat reads

    // ---------------- phase 2: splat (lane = pixel) ----------------
    const int h = lane >> 3, w = lane & 7;
    const int ppix = (h + 1) * 10 + (w + 1);       // padded 10x10 pixel index
    const float gx = -1.0f + w * (2.0f / 7.0f);
    const float gy = -1.0f + h * (2.0f / 7.0f);
    const float tau = fast_softplus(tau_raw[0]) + 0.06f;
    const float fl2 = -0.721347520f * fast_rcp(tau * tau);   // -0.5*log2e/tau^2

    float pos0 = 0.0f, pos1 = 0.0f, shp0 = 0.0f, shp1 = 0.0f;
    #pragma unroll 4
    for (int n = 0; n < 64; ++n) {
        float4 q0 = qbuf[wave][0][n];
        float du = q0.x - gx, dv = q0.y - gy;
        float e  = fast_exp2(fl2 * (du*du + dv*dv));
        pos0 = fmaf(q0.z, e, pos0); shp0 = fmaf(q0.w, e, shp0);
        float4 q1 = qbuf[wave][1][n];
        du = q1.x - gx; dv = q1.y - gy;
        e  = fast_exp2(fl2 * (du*du + dv*dv));
        pos1 = fmaf(q1.z, e, pos1); shp1 = fmaf(q1.w, e, shp1);
    }
    __syncthreads();   // CRITICAL: splat reads of qbuf complete before the
                       // aliased float-typed overwrite below (compiler WAR fence)

    // alias qbuf[wave] as padded input image: inbw[4 ch][100 padpix] f32
    float* inbw = (float*)&qbuf[wave][0][0];
    #pragma unroll
    for (int j = 0; j < 7; ++j) {                  // zero 400 floats (borders)
        int idx = lane + j*64;
        if (idx < 400) inbw[idx] = 0.0f;
    }
    inbw[  0 + ppix] = pos0;
    inbw[100 + ppix] = pos1;
    inbw[200 + ppix] = shp0;
    inbw[300 + ppix] = shp1;

    // ---- per-block preloads ----
    const float* w1p = w1 + k*32*2*9;
    const int g  = lane >> 4;                      // K-chunk group for MFMA frags
    const int r15 = lane & 15;
    float b2v[8], wfv[8];
    #pragma unroll
    for (int mt = 0; mt < 2; ++mt)
        #pragma unroll
        for (int r = 0; r < 4; ++r) {
            int oc = mt*16 + g*4 + r;
            b2v[mt*4+r] = b2[k*32 + oc];
            wfv[mt*4+r] = wf[k*32 + oc];
        }
    const float bfv = bfp[k];

    short* h1w = &h1c[wave][0];
    float results[2];

    #pragma unroll
    for (int s = 0; s < 2; ++s) {
        __syncthreads();   // order inbw/h1 writes vs reads across types & phases
        // ---- conv1 (f32 VALU, weights scalar-loaded) ----
        float g1[32];
        {
            float nb[18];
            #pragma unroll
            for (int ch = 0; ch < 2; ++ch)
                #pragma unroll
                for (int tap = 0; tap < 9; ++tap)
                    nb[ch*9+tap] = inbw[(2*s+ch)*100 + ppix + (tap/3 - 1)*10 + (tap%3 - 1)];
            #pragma unroll
            for (int oc = 0; oc < 32; ++oc) {
                float acc = b1[k*32 + oc];
                #pragma unroll
                for (int q = 0; q < 18; ++q)
                    acc = fmaf(w1p[oc*18 + q], nb[q], acc);
                g1[oc] = fast_gelu(acc);
            }
        }
        // ---- pack h1 -> bf16, store padded image [kc][padpix][8ic] ----
        #pragma unroll
        for (int kc = 0; kc < 4; ++kc) {
            bf16x8 v;
            #pragma unroll
            for (int j = 0; j < 8; ++j) v[j] = f2bf(g1[kc*8 + j]);
            *(bf16x8*)&h1w[kc*800 + ppix*8] = v;
        }
        __syncthreads();   // h1 writes ordered before conv2 fragment reads

        // ---- conv2: 9 shifted 32x32x64 GEMMs via MFMA ----
        f32x4 acc[2][4];
        #pragma unroll
        for (int mt = 0; mt < 2; ++mt)
            #pragma unroll
            for (int nt = 0; nt < 4; ++nt) acc[mt][nt] = (f32x4)0.0f;

        const short* w2g = &w2s[g * W2SS];
        const short* h1g = &h1w[g * 800];
        const int prow0 = (lane >> 3) & 1;         // row within an nt pair
        const int pb    = (prow0 + 1)*10 + (lane & 7) + 1;

        #pragma unroll
        for (int tap = 0; tap < 9; ++tap) {
            const int dy = tap/3 - 1, dx = tap%3 - 1;
            bf16x8 a0 = *(const bf16x8*)&w2g[(tap*32 +      r15)*8];
            bf16x8 a1 = *(const bf16x8*)&w2g[(tap*32 + 16 + r15)*8];
            const short* bp = &h1g[(pb + dy*10 + dx)*8];
            bf16x8 bv0 = *(const bf16x8*)&bp[0];
            bf16x8 bv1 = *(const bf16x8*)&bp[160];
            bf16x8 bv2 = *(const bf16x8*)&bp[320];
            bf16x8 bv3 = *(const bf16x8*)&bp[480];
            acc[0][0] = __builtin_amdgcn_mfma_f32_16x16x32_bf16(a0, bv0, acc[0][0], 0, 0, 0);
            acc[1][0] = __builtin_amdgcn_mfma_f32_16x16x32_bf16(a1, bv0, acc[1][0], 0, 0, 0);
            acc[0][1] = __builtin_amdgcn_mfma_f32_16x16x32_bf16(a0, bv1, acc[0][1], 0, 0, 0);
            acc[1][1] = __builtin_amdgcn_mfma_f32_16x16x32_bf16(a1, bv1, acc[1][1], 0, 0, 0);
            acc[0][2] = __builtin_amdgcn_mfma_f32_16x16x32_bf16(a0, bv2, acc[0][2], 0, 0, 0);
            acc[1][2] = __builtin_amdgcn_mfma_f32_16x16x32_bf16(a1, bv2, acc[1][2], 0, 0, 0);
            acc[0][3] = __builtin_amdgcn_mfma_f32_16x16x32_bf16(a0, bv3, acc[0][3], 0, 0, 0);
            acc[1][3] = __builtin_amdgcn_mfma_f32_16x16x32_bf16(a1, bv3, acc[1][3], 0, 0, 0);
        }

        // ---- epilogue: bias + gelu + wf dot + mean (full-wave reduce) ----
        float p = 0.0f;
        #pragma unroll
        for (int mt = 0; mt < 2; ++mt)
            #pragma unroll
            for (int nt = 0; nt < 4; ++nt)
                #pragma unroll
                for (int r = 0; r < 4; ++r)
                    p = fmaf(fast_gelu(acc[mt][nt][r] + b2v[mt*4+r]), wfv[mt*4+r], p);
        #pragma unroll
        for (int off = 32; off >= 1; off >>= 1)
            p += __shfl_xor(p, off, 64);
        results[s] = bfv + p * (1.0f / 64.0f);
    }

    if (lane == 0) {
        out[(b*TT + i      ) * KK + k] = results[0];
        out[(b*TT + i + 512) * KK + k] = results[1];
    }
}

// ---------------------------------------------------------------------------
extern "C" void kernel_launch(void* const* d_in, const int* in_sizes, int n_in,
                              void* d_out, int out_size, void* d_ws, size_t ws_size,
                              hipStream_t stream)
{
    const float* mu            = (const float*)d_in[0];
    const float* sigma0        = (const float*)d_in[1];
    const float* sigma_vel     = (const float*)d_in[2];
    const float* amplitude     = (const float*)d_in[3];
    const float* sh_base       = (const float*)d_in[4];
    const float* sh_vel        = (const float*)d_in[5];
    const float* p0            = (const float*)d_in[6];
    const float* p_vel         = (const float*)d_in[7];
    const float* chest_offset  = (const float*)d_in[8];
    const float* resp_freq     = (const float*)d_in[9];
    const float* resp_vec      = (const float*)d_in[10];
    const float* tau_raw       = (const float*)d_in[11];
    const float* limb_ra       = (const float*)d_in[12];
    const float* limb_la       = (const float*)d_in[13];
    const float* limb_ll       = (const float*)d_in[14];
    const float* chest_vectors = (const float*)d_in[15];
    const float* w1            = (const float*)d_in[16];
    const float* b1            = (const float*)d_in[17];
    const float* w2            = (const float*)d_in[18];
    const float* b2            = (const float*)d_in[19];
    const float* wf            = (const float*)d_in[20];
    const float* bfp           = (const float*)d_in[21];

    float*          lead = (float*)d_ws;                      // 18*BKT f32
    unsigned short* w2bf = (unsigned short*)(lead + 18*BKT);  // 110592 u16

    hipLaunchKernelGGL(prep_lead, dim3(BKT/256), dim3(256), 0, stream,
                       chest_offset, resp_freq, resp_vec,
                       limb_ra, limb_la, limb_ll, chest_vectors, lead);
    hipLaunchKernelGGL(prep_w2bf, dim3((KK*4*9*32*8 + 255)/256), dim3(256), 0, stream, w2, w2bf);
    hipLaunchKernelGGL(fused_main, dim3(BB*KK*128), dim3(256), 0, stream,
                       mu, sigma0, sigma_vel, amplitude, sh_base, sh_vel, p0, p_vel,
                       tau_raw, w1, b1, w2bf, b2, wf, bfp, lead, (float*)d_out);
}

// Round 8
// 539.050 us; speedup vs baseline: 1.3757x; 1.3757x over previous
//
#include <hip/hip_runtime.h>
#include <hip/hip_bf16.h>
#include <math.h>

#define BB 8
#define NN 64
#define TT 1024
#define KK 12
#define BKT (BB*KK*TT)   // 98304
#define W2SS 2312        // shorts per kc chunk in LDS w2s

// Compiler-only memory fence: zero instructions, pins LDS op order across
// type-punned per-wave handoffs (R6 failure mode). HW needs nothing: same-wave
// LDS ops are in-order.
#define WAVE_FENCE() asm volatile("" ::: "memory")

typedef short bf16x8 __attribute__((ext_vector_type(8)));
typedef float f32x4  __attribute__((ext_vector_type(4)));

__device__ __forceinline__ float fast_rcp(float x)  { return __builtin_amdgcn_rcpf(x); }
__device__ __forceinline__ float fast_exp2(float x) { return __builtin_amdgcn_exp2f(x); }
__device__ __forceinline__ float fast_log2(float x) { return __builtin_amdgcn_logf(x); }

__device__ __forceinline__ float fast_softplus(float x) {
    float a = fabsf(x);
    float e = fast_exp2(-1.44269504f * a);
    float l = fast_log2(1.0f + e) * 0.69314718f;
    return fmaxf(x, 0.0f) + l;
}
__device__ __forceinline__ float fast_tanh(float x) {
    float t = fast_exp2(x * 2.885390082f);       // e^(2x)
    return fmaf(-2.0f, fast_rcp(t + 1.0f), 1.0f);
}
// Abramowitz-Stegun 7.1.26, |err| <= 1.5e-7
__device__ __forceinline__ float fast_erf(float x) {
    float ax = fabsf(x);
    float t  = fast_rcp(fmaf(0.3275911f, ax, 1.0f));
    float p  = fmaf(fmaf(fmaf(fmaf(1.061405429f, t, -1.453152027f), t,
                   1.421413741f), t, -0.284496736f), t, 0.254829592f) * t;
    float e  = fast_exp2(-1.44269504f * ax * ax);
    float r  = fmaf(-p, e, 1.0f);
    return copysignf(r, x);
}
__device__ __forceinline__ float fast_gelu(float x) {
    return 0.5f * x * (1.0f + fast_erf(x * 0.70710678118654752f));
}
__device__ __forceinline__ short f2bf(float x) {
    return (short)__builtin_bit_cast(unsigned short, __float2bfloat16(x));
}

// ---------------------------------------------------------------------------
// Kernel 1: per-(b,k,t) lead geometry -> ws: lead[18][BKT]
// ---------------------------------------------------------------------------
__global__ void prep_lead(const float* __restrict__ chest_offset,
                          const float* __restrict__ resp_freq,
                          const float* __restrict__ resp_vec,
                          const float* __restrict__ limb_ra,
                          const float* __restrict__ limb_la,
                          const float* __restrict__ limb_ll,
                          const float* __restrict__ chest_vectors,
                          float* __restrict__ lead)
{
    int id = blockIdx.x * blockDim.x + threadIdx.x;
    if (id >= BKT) return;
    int t  = id & (TT - 1);
    int bk = id >> 10;
    int k  = bk % KK;
    int b  = bk / KK;

    float lx, ly, lz;
    if (k < 6) {
        float rax = limb_ra[0], ray = limb_ra[1], raz = limb_ra[2];
        float lax = limb_la[0], lay = limb_la[1], laz = limb_la[2];
        float llx = limb_ll[0], lly = limb_ll[1], llz = limb_ll[2];
        float dx, dy, dz;
        switch (k) {
            case 0: dx = lax - rax; dy = lay - ray; dz = laz - raz; break;
            case 1: dx = llx - rax; dy = lly - ray; dz = llz - raz; break;
            case 2: dx = llx - lax; dy = lly - lay; dz = llz - laz; break;
            case 3: dx = rax - 0.5f*(lax+llx); dy = ray - 0.5f*(lay+lly); dz = raz - 0.5f*(laz+llz); break;
            case 4: dx = lax - 0.5f*(rax+llx); dy = lay - 0.5f*(ray+lly); dz = laz - 0.5f*(raz+llz); break;
            default:dx = llx - 0.5f*(rax+lax); dy = lly - 0.5f*(ray+lay); dz = llz - 0.5f*(raz+laz); break;
        }
        float n   = sqrtf(dx*dx + dy*dy + dz*dz);
        float inv = 1.0f / fmaxf(n, 1e-6f);
        lx = dx*inv; ly = dy*inv; lz = dz*inv;
    } else {
        int j = k - 6;
        float cx = chest_vectors[j*3+0], cy = chest_vectors[j*3+1], cz = chest_vectors[j*3+2];
        float n   = sqrtf(cx*cx + cy*cy + cz*cz);
        float inv = 1.0f / fmaxf(n, 1e-12f);
        cx *= inv; cy *= inv; cz *= inv;
        cx += chest_offset[(b*6+j)*3+0];
        cy += chest_offset[(b*6+j)*3+1];
        cz += chest_offset[(b*6+j)*3+2];
        n   = sqrtf(cx*cx + cy*cy + cz*cz);
        inv = 1.0f / fmaxf(n, 1e-12f);
        lx = cx*inv; ly = cy*inv; lz = cz*inv;
    }

    float tl = t * (1.0f / (TT - 1));
    float ph = 6.283185307179586f * resp_freq[b] * tl;
    float sv = sinf(ph);
    float Lx = lx + resp_vec[b*3+0] * sv;
    float Ly = ly + resp_vec[b*3+1] * sv;
    float Lz = lz + resp_vec[b*3+2] * sv;
    float n   = sqrtf(Lx*Lx + Ly*Ly + Lz*Lz);
    float inv = 1.0f / fmaxf(n, 1e-12f);
    Lx *= inv; Ly *= inv; Lz *= inv;

    float e1x = 0.0f, e1y = Lz, e1z = -Ly;
    float n1  = sqrtf(e1y*e1y + e1z*e1z);
    if (n1 < 1e-4f) { e1x = -Lz; e1y = 0.0f; e1z = Lx; }
    float ne1 = sqrtf(e1x*e1x + e1y*e1y + e1z*e1z);
    inv = 1.0f / fmaxf(ne1, 1e-6f);
    e1x *= inv; e1y *= inv; e1z *= inv;

    float e2x = e1y*Lz - e1z*Ly;
    float e2y = e1z*Lx - e1x*Lz;
    float e2z = e1x*Ly - e1y*Lx;
    float ne2 = sqrtf(e2x*e2x + e2y*e2y + e2z*e2z);
    inv = 1.0f / fmaxf(ne2, 1e-6f);
    e2x *= inv; e2y *= inv; e2z *= inv;

    lead[ 0*BKT + id] = Lx;
    lead[ 1*BKT + id] = Ly;
    lead[ 2*BKT + id] = Lz;
    lead[ 3*BKT + id] = e1x;
    lead[ 4*BKT + id] = e1y;
    lead[ 5*BKT + id] = e1z;
    lead[ 6*BKT + id] = e2x;
    lead[ 7*BKT + id] = e2y;
    lead[ 8*BKT + id] = e2z;
    lead[ 9*BKT + id] = 0.282095f;
    lead[10*BKT + id] = -0.488603f * Ly;
    lead[11*BKT + id] =  0.488603f * Lz;
    lead[12*BKT + id] = -0.488603f * Lx;
    lead[13*BKT + id] =  1.092548f * Lx * Ly;
    lead[14*BKT + id] = -1.092548f * Ly * Lz;
    lead[15*BKT + id] =  0.315392f * (3.0f * Lz * Lz - 1.0f);
    lead[16*BKT + id] = -1.092548f * Lx * Lz;
    lead[17*BKT + id] =  0.546274f * (Lx * Lx - Ly * Ly);
}

// ---------------------------------------------------------------------------
// Kernel 2: w2 [k][oc][ic][tap] f32 -> w2bf [k][kc][tap][oc][8ic] bf16
// ---------------------------------------------------------------------------
__global__ void prep_w2bf(const float* __restrict__ w2, unsigned short* __restrict__ out)
{
    int id = blockIdx.x * blockDim.x + threadIdx.x;
    if (id >= KK*4*9*32*8) return;
    int j   = id & 7;
    int r1  = id >> 3;
    int oc  = r1 & 31;
    int r2  = r1 >> 5;
    int tap = r2 % 9;
    int r3  = r2 / 9;
    int kc  = r3 & 3;
    int k   = r3 >> 2;
    float v = w2[((k*32 + oc)*32 + (kc*8 + j))*9 + tap];
    out[id] = __builtin_bit_cast(unsigned short, __float2bfloat16(v));
}

// ---------------------------------------------------------------------------
// Kernel 3: fused splat + CNN (conv2 via bf16 MFMA 16x16x32).
// [round-2 structure + fast transcendentals + per-wave compiler fences]
// ---------------------------------------------------------------------------
__global__ __launch_bounds__(256, 3) void fused_main(
    const float* __restrict__ mu,       const float* __restrict__ sigma0,
    const float* __restrict__ sigma_vel,const float* __restrict__ amplitude,
    const float* __restrict__ sh_base,  const float* __restrict__ sh_vel,
    const float* __restrict__ p0,       const float* __restrict__ p_vel,
    const float* __restrict__ tau_raw,
    const float* __restrict__ w1,       const float* __restrict__ b1,
    const unsigned short* __restrict__ w2bf, const float* __restrict__ b2,
    const float* __restrict__ wf,       const float* __restrict__ bfp,
    const float* __restrict__ lead,     float* __restrict__ out)
{
    // LDS: 18496 + 25600 + 8192 = 52288 B -> 3 blocks/CU
    __shared__ __align__(16) short  w2s[4*W2SS];     // [kc][tap][oc][8ic] bf16, padded stride
    __shared__ __align__(16) short  h1c[4][3200];    // per wave: [kc=4][100 padpix][8 ic] bf16
    __shared__ __align__(16) float4 qbuf[4][2][64];  // per wave: phase1 out; later aliased as padded inb

    const int wave = threadIdx.x >> 6;
    const int lane = threadIdx.x & 63;
    const int bid  = blockIdx.x;
    const int ig   = bid & 127;
    const int k    = (bid >> 7) % KK;
    const int b    = bid / (128 * KK);
    const int i    = ig * 4 + wave;
    const int t0   = 2 * i;

    // ---- stage w2 bf16 fragments into LDS (block-shared) ----
    {
        const unsigned* w2u = (const unsigned*)(w2bf + k * 9216);
        for (int idx = threadIdx.x; idx < 4608; idx += 256) {
            unsigned v = w2u[idx];
            int sp  = idx << 1;
            int kc  = sp / 2304;
            int rem = sp - kc * 2304;
            *(unsigned*)&w2s[kc * W2SS + rem] = v;
        }
    }
    // ---- zero this wave's h1c (border stays 0 forever) ----
    {
        unsigned* hz = (unsigned*)&h1c[wave][0];
        #pragma unroll
        for (int j = 0; j < 25; ++j) hz[lane + j*64] = 0u;
    }
    __syncthreads();   // the only block-wide barrier (w2s is block-shared)

    // ---------------- phase 1: per-n quantities (lane = n) ----------------
    {
        const int n  = lane;
        const int bn = b * NN + n;
        const float muv = mu[bn], s0v = sigma0[bn], svv = sigma_vel[bn], amp = amplitude[bn];
        const float p0x = p0[bn*3+0], p0y = p0[bn*3+1], p0z = p0[bn*3+2];
        const float pvx = p_vel[bn*3+0], pvy = p_vel[bn*3+1], pvz = p_vel[bn*3+2];
        float shb[9], shv[9];
        #pragma unroll
        for (int m = 0; m < 9; ++m) { shb[m] = sh_base[bn*9+m]; shv[m] = sh_vel[bn*9+m]; }

        #pragma unroll
        for (int tt = 0; tt < 2; ++tt) {
            const int t  = t0 + tt;
            const int li = (b*KK + k)*TT + t;      // wave-uniform -> s_load
            const float Lx  = lead[0*BKT+li], Ly  = lead[1*BKT+li], Lz  = lead[2*BKT+li];
            const float e1x = lead[3*BKT+li], e1y = lead[4*BKT+li], e1z = lead[5*BKT+li];
            const float e2x = lead[6*BKT+li], e2y = lead[7*BKT+li], e2z = lead[8*BKT+li];
            float Yv[9];
            #pragma unroll
            for (int m = 0; m < 9; ++m) Yv[m] = lead[(9+m)*BKT + li];

            const float tl = t * (1.0f / (TT - 1));
            const float dt = tl - muv;
            const float sig = fast_softplus(s0v + svv*dt) + 0.001f;
            const float z   = dt * fast_rcp(sig);
            const float g   = amp * fast_exp2(-0.721347520f * z * z);
            float px = p0x + pvx*dt, py = p0y + pvy*dt, pz = p0z + pvz*dt;
            const float pn   = sqrtf(px*px + py*py + pz*pz);
            const float pinv = fast_rcp(fmaxf(pn, 1e-6f));
            px *= pinv; py *= pinv; pz *= pinv;
            const float u    = fast_tanh(px*e1x + py*e1y + pz*e1z);
            const float v    = fast_tanh(px*e2x + py*e2y + pz*e2z);
            const float hem  = fmaxf(px*Lx + py*Ly + pz*Lz, 0.0f);
            const float a    = g * hem;
            float shp = 0.0f;
            #pragma unroll
            for (int m = 0; m < 9; ++m) shp = fmaf(fmaf(shv[m], dt, shb[m]), Yv[m], shp);
            qbuf[wave][tt][n] = make_float4(u, v, a, a * shp);
        }
    }
    WAVE_FENCE();      // qbuf writes ordered before splat reads (same wave)

    // ---------------- phase 2: splat (lane = pixel) ----------------
    const int h = lane >> 3, w = lane & 7;
    const int ppix = (h + 1) * 10 + (w + 1);       // padded 10x10 pixel index
    const float gx = -1.0f + w * (2.0f / 7.0f);
    const float gy = -1.0f + h * (2.0f / 7.0f);
    const float tau = fast_softplus(tau_raw[0]) + 0.06f;
    const float fl2 = -0.721347520f * fast_rcp(tau * tau);   // -0.5*log2e/tau^2

    float pos0 = 0.0f, pos1 = 0.0f, shp0 = 0.0f, shp1 = 0.0f;
    #pragma unroll 4
    for (int n = 0; n < 64; ++n) {
        float4 q0 = qbuf[wave][0][n];
        float du = q0.x - gx, dv = q0.y - gy;
        float e  = fast_exp2(fl2 * (du*du + dv*dv));
        pos0 = fmaf(q0.z, e, pos0); shp0 = fmaf(q0.w, e, shp0);
        float4 q1 = qbuf[wave][1][n];
        du = q1.x - gx; dv = q1.y - gy;
        e  = fast_exp2(fl2 * (du*du + dv*dv));
        pos1 = fmaf(q1.z, e, pos1); shp1 = fmaf(q1.w, e, shp1);
    }
    WAVE_FENCE();      // splat reads of qbuf complete (in program order) before
                       // the aliased float-typed overwrite below

    // alias qbuf[wave] as padded input image: inbw[4 ch][100 padpix] f32
    float* inbw = (float*)&qbuf[wave][0][0];
    #pragma unroll
    for (int j = 0; j < 7; ++j) {                  // zero 400 floats (borders)
        int idx = lane + j*64;
        if (idx < 400) inbw[idx] = 0.0f;
    }
    inbw[  0 + ppix] = pos0;
    inbw[100 + ppix] = pos1;
    inbw[200 + ppix] = shp0;
    inbw[300 + ppix] = shp1;
    WAVE_FENCE();      // inbw writes ordered before conv1 reads (same wave)

    // ---- per-block preloads ----
    const float* w1p = w1 + k*32*2*9;
    const int g  = lane >> 4;                      // K-chunk group for MFMA frags
    const int r15 = lane & 15;
    float b2v[8], wfv[8];
    #pragma unroll
    for (int mt = 0; mt < 2; ++mt)
        #pragma unroll
        for (int r = 0; r < 4; ++r) {
            int oc = mt*16 + g*4 + r;
            b2v[mt*4+r] = b2[k*32 + oc];
            wfv[mt*4+r] = wf[k*32 + oc];
        }
    const float bfv = bfp[k];

    short* h1w = &h1c[wave][0];
    float results[2];

    #pragma unroll
    for (int s = 0; s < 2; ++s) {
        // ---- conv1 (f32 VALU, weights scalar-loaded) ----
        float g1[32];
        {
            float nb[18];
            #pragma unroll
            for (int ch = 0; ch < 2; ++ch)
                #pragma unroll
                for (int tap = 0; tap < 9; ++tap)
                    nb[ch*9+tap] = inbw[(2*s+ch)*100 + ppix + (tap/3 - 1)*10 + (tap%3 - 1)];
            #pragma unroll
            for (int oc = 0; oc < 32; ++oc) {
                float acc = b1[k*32 + oc];
                #pragma unroll
                for (int q = 0; q < 18; ++q)
                    acc = fmaf(w1p[oc*18 + q], nb[q], acc);
                g1[oc] = fast_gelu(acc);
            }
        }
        // ---- pack h1 -> bf16, store padded image [kc][padpix][8ic] ----
        #pragma unroll
        for (int kc = 0; kc < 4; ++kc) {
            bf16x8 v;
            #pragma unroll
            for (int j = 0; j < 8; ++j) v[j] = f2bf(g1[kc*8 + j]);
            *(bf16x8*)&h1w[kc*800 + ppix*8] = v;
        }
        WAVE_FENCE();  // h1 writes ordered before conv2 fragment reads (same wave)

        // ---- conv2: 9 shifted 32x32x64 GEMMs via MFMA ----
        f32x4 acc[2][4];
        #pragma unroll
        for (int mt = 0; mt < 2; ++mt)
            #pragma unroll
            for (int nt = 0; nt < 4; ++nt) acc[mt][nt] = (f32x4)0.0f;

        const short* w2g = &w2s[g * W2SS];
        const short* h1g = &h1w[g * 800];
        const int prow0 = (lane >> 3) & 1;         // row within an nt pair
        const int pb    = (prow0 + 1)*10 + (lane & 7) + 1;

        #pragma unroll
        for (int tap = 0; tap < 9; ++tap) {
            const int dy = tap/3 - 1, dx = tap%3 - 1;
            bf16x8 a0 = *(const bf16x8*)&w2g[(tap*32 +      r15)*8];
            bf16x8 a1 = *(const bf16x8*)&w2g[(tap*32 + 16 + r15)*8];
            const short* bp = &h1g[(pb + dy*10 + dx)*8];
            bf16x8 bv0 = *(const bf16x8*)&bp[0];
            bf16x8 bv1 = *(const bf16x8*)&bp[160];
            bf16x8 bv2 = *(const bf16x8*)&bp[320];
            bf16x8 bv3 = *(const bf16x8*)&bp[480];
            acc[0][0] = __builtin_amdgcn_mfma_f32_16x16x32_bf16(a0, bv0, acc[0][0], 0, 0, 0);
            acc[1][0] = __builtin_amdgcn_mfma_f32_16x16x32_bf16(a1, bv0, acc[1][0], 0, 0, 0);
            acc[0][1] = __builtin_amdgcn_mfma_f32_16x16x32_bf16(a0, bv1, acc[0][1], 0, 0, 0);
            acc[1][1] = __builtin_amdgcn_mfma_f32_16x16x32_bf16(a1, bv1, acc[1][1], 0, 0, 0);
            acc[0][2] = __builtin_amdgcn_mfma_f32_16x16x32_bf16(a0, bv2, acc[0][2], 0, 0, 0);
            acc[1][2] = __builtin_amdgcn_mfma_f32_16x16x32_bf16(a1, bv2, acc[1][2], 0, 0, 0);
            acc[0][3] = __builtin_amdgcn_mfma_f32_16x16x32_bf16(a0, bv3, acc[0][3], 0, 0, 0);
            acc[1][3] = __builtin_amdgcn_mfma_f32_16x16x32_bf16(a1, bv3, acc[1][3], 0, 0, 0);
        }
        WAVE_FENCE();  // conv2 h1 reads complete before next s-iteration overwrites h1

        // ---- epilogue: bias + gelu + wf dot + mean (full-wave reduce) ----
        float p = 0.0f;
        #pragma unroll
        for (int mt = 0; mt < 2; ++mt)
            #pragma unroll
            for (int nt = 0; nt < 4; ++nt)
                #pragma unroll
                for (int r = 0; r < 4; ++r)
                    p = fmaf(fast_gelu(acc[mt][nt][r] + b2v[mt*4+r]), wfv[mt*4+r], p);
        #pragma unroll
        for (int off = 32; off >= 1; off >>= 1)
            p += __shfl_xor(p, off, 64);
        results[s] = bfv + p * (1.0f / 64.0f);
    }

    if (lane == 0) {
        out[(b*TT + i      ) * KK + k] = results[0];
        out[(b*TT + i + 512) * KK + k] = results[1];
    }
}

// ---------------------------------------------------------------------------
extern "C" void kernel_launch(void* const* d_in, const int* in_sizes, int n_in,
                              void* d_out, int out_size, void* d_ws, size_t ws_size,
                              hipStream_t stream)
{
    const float* mu            = (const float*)d_in[0];
    const float* sigma0        = (const float*)d_in[1];
    const float* sigma_vel     = (const float*)d_in[2];
    const float* amplitude     = (const float*)d_in[3];
    const float* sh_base       = (const float*)d_in[4];
    const float* sh_vel        = (const float*)d_in[5];
    const float* p0            = (const float*)d_in[6];
    const float* p_vel         = (const float*)d_in[7];
    const float* chest_offset  = (const float*)d_in[8];
    const float* resp_freq     = (const float*)d_in[9];
    const float* resp_vec      = (const float*)d_in[10];
    const float* tau_raw       = (const float*)d_in[11];
    const float* limb_ra       = (const float*)d_in[12];
    const float* limb_la       = (const float*)d_in[13];
    const float* limb_ll       = (const float*)d_in[14];
    const float* chest_vectors = (const float*)d_in[15];
    const float* w1            = (const float*)d_in[16];
    const float* b1            = (const float*)d_in[17];
    const float* w2            = (const float*)d_in[18];
    const float* b2            = (const float*)d_in[19];
    const float* wf            = (const float*)d_in[20];
    const float* bfp           = (const float*)d_in[21];

    float*          lead = (float*)d_ws;                      // 18*BKT f32
    unsigned short* w2bf = (unsigned short*)(lead + 18*BKT);  // 110592 u16

    hipLaunchKernelGGL(prep_lead, dim3(BKT/256), dim3(256), 0, stream,
                       chest_offset, resp_freq, resp_vec,
                       limb_ra, limb_la, limb_ll, chest_vectors, lead);
    hipLaunchKernelGGL(prep_w2bf, dim3((KK*4*9*32*8 + 255)/256), dim3(256), 0, stream, w2, w2bf);
    hipLaunchKernelGGL(fused_main, dim3(BB*KK*128), dim3(256), 0, stream,
                       mu, sigma0, sigma_vel, amplitude, sh_base, sh_vel, p0, p_vel,
                       tau_raw, w1, b1, w2bf, b2, wf, bfp, lead, (float*)d_out);
}